// Round 1
// baseline (310.755 us; speedup 1.0000x reference)
//
#include <hip/hip_runtime.h>
#include <hip/hip_bf16.h>
#include <math.h>

#define B_  4
#define T_  4096
#define C_  1024
#define HS_ 128

using bf16x8 = __attribute__((ext_vector_type(8))) __bf16;
using bf16x4 = __attribute__((ext_vector_type(4))) __bf16;
using f32x4  = __attribute__((ext_vector_type(4))) float;

#define MFMA(a, b, c) __builtin_amdgcn_mfma_f32_16x16x32_bf16(a, b, c, 0, 0, 0)

// ---------------------------------------------------------------------------
// Kernel 1: W fp32 [1024][128] -> Wt bf16 [3][128][1024] (transposed, K-contig)
// m=0: Wq (scaled by 1/sqrt(128)), m=1: Wk, m=2: Wv
// ---------------------------------------------------------------------------
__global__ __launch_bounds__(256) void prep_w_kernel(
    const float* __restrict__ Wk, const float* __restrict__ Wq,
    const float* __restrict__ Wv, __bf16* __restrict__ Wt) {
  int idx = blockIdx.x * 256 + threadIdx.x;     // 1536*256 = 393216 = 3*128*1024
  int m   = idx >> 17;
  int rem = idx & 131071;
  int n   = rem >> 10;
  int k   = rem & 1023;
  const float* W = (m == 0) ? Wq : ((m == 1) ? Wk : Wv);
  float v = W[k * HS_ + n];
  if (m == 0) v *= 0.08838834764831845f;        // fold attn scale into Q
  Wt[idx] = (__bf16)v;
}

__device__ inline bf16x8 cvt8(const float* p) {
  float4 u = *reinterpret_cast<const float4*>(p);
  float4 v = *reinterpret_cast<const float4*>(p + 4);
  bf16x8 r;
  r[0] = (__bf16)u.x; r[1] = (__bf16)u.y; r[2] = (__bf16)u.z; r[3] = (__bf16)u.w;
  r[4] = (__bf16)v.x; r[5] = (__bf16)v.y; r[6] = (__bf16)v.z; r[7] = (__bf16)v.w;
  return r;
}

// ---------------------------------------------------------------------------
// Kernel 2: projections. blockIdx.y = matrix (0=Q,1=K,2=V).
// Each wave: 32 rows x 128 cols, K-loop over 1024 in steps of 32.
// A-frag: 8 contiguous fp32 of x converted to bf16 in-register.
// B-frag: 8 contiguous bf16 of Wt row (= W column).
// Q,K written row-major bf16 [B*T][128]; V written transposed [B][128][T].
// ---------------------------------------------------------------------------
__global__ __launch_bounds__(256) void proj_kernel(
    const float* __restrict__ x, const __bf16* __restrict__ Wt,
    __bf16* __restrict__ Qb, __bf16* __restrict__ Kb, __bf16* __restrict__ Vt) {
  const int tid = threadIdx.x;
  const int wid = tid >> 6;
  const int l   = tid & 63;
  const int c   = l & 15;      // A-row / B-col slot
  const int g   = l >> 4;      // k-group
  const int m   = blockIdx.y;
  const int rbase = blockIdx.x * 128 + wid * 32;

  f32x4 acc[2][8];
#pragma unroll
  for (int i = 0; i < 2; ++i)
#pragma unroll
    for (int j = 0; j < 8; ++j) acc[i][j] = 0.f;

  const float*  xr0 = x + (size_t)(rbase + c) * C_;
  const float*  xr1 = xr0 + 16 * C_;
  const __bf16* wb  = Wt + ((size_t)m * 128 + c) * C_;

  for (int cb = 0; cb < C_; cb += 32) {
    const int co = cb + g * 8;
    bf16x8 a0 = cvt8(xr0 + co);
    bf16x8 a1 = cvt8(xr1 + co);
#pragma unroll
    for (int nt = 0; nt < 8; ++nt) {
      bf16x8 bf = *reinterpret_cast<const bf16x8*>(wb + nt * 16 * C_ + co);
      acc[0][nt] = MFMA(a0, bf, acc[0][nt]);
      acc[1][nt] = MFMA(a1, bf, acc[1][nt]);
    }
  }

  if (m < 2) {
    __bf16* dst = (m == 0) ? Qb : Kb;
#pragma unroll
    for (int rt = 0; rt < 2; ++rt)
#pragma unroll
      for (int nt = 0; nt < 8; ++nt)
#pragma unroll
        for (int r = 0; r < 4; ++r) {
          int row = rbase + rt * 16 + 4 * g + r;   // D row = 4g+r
          dst[(size_t)row * HS_ + nt * 16 + c] = (__bf16)acc[rt][nt][r];
        }
  } else {
#pragma unroll
    for (int rt = 0; rt < 2; ++rt)
#pragma unroll
      for (int nt = 0; nt < 8; ++nt) {
        int row = rbase + rt * 16 + 4 * g;          // 4 consecutive rows
        int bb  = row >> 12;
        int t   = row & 4095;
        int n   = nt * 16 + c;
        bf16x4 v4;
#pragma unroll
        for (int r = 0; r < 4; ++r) v4[r] = (__bf16)acc[rt][nt][r];
        *reinterpret_cast<bf16x4*>(Vt + ((size_t)bb * HS_ + n) * T_ + t) = v4;
      }
  }
}

// ---------------------------------------------------------------------------
// Kernel 3: causal flash attention. 1 wave (64 thr) per 32 q-rows.
// S^T = mfma(A=K_perm, B=Q^T): lane(g,c) reg r of mfma mm holds
//   S^T[key = kbase+8g+4mm+r][q = qb+rt*16+c]   (key-permuted A feed)
// -> softmax stats per q are lane-column-local (2 shuffles per reduce)
// -> P packed per-lane IS the B-frag of P^T for PV (zero cross-lane).
// O^T = mfma(A=V^T, B=P^T), epilogue transposes via padded LDS.
// ---------------------------------------------------------------------------
__global__ __launch_bounds__(64) void attn_kernel(
    const __bf16* __restrict__ Qb, const __bf16* __restrict__ Kb,
    const __bf16* __restrict__ Vt, float* __restrict__ out) {
  __shared__ float lds[32 * 129];
  const int l  = threadIdx.x;
  const int c  = l & 15;
  const int g  = l >> 4;
  const int bid = blockIdx.x;
  const int b  = bid >> 7;
  const int qt = 127 - (bid & 127);   // largest q-tile first (load balance)
  const int qb = qt * 32;
  const int kp = ((l & 12) << 1) | (l & 3);  // A-slot m -> key 8*(m>>2)+(m&3)

  const __bf16* Qp = Qb + (size_t)b * T_ * HS_;
  const __bf16* Kp = Kb + (size_t)b * T_ * HS_;
  const __bf16* Vp = Vt + (size_t)b * HS_ * T_;

  bf16x8 qf[2][4];
#pragma unroll
  for (int rt = 0; rt < 2; ++rt)
#pragma unroll
    for (int cs = 0; cs < 4; ++cs)
      qf[rt][cs] = *reinterpret_cast<const bf16x8*>(
          Qp + (qb + rt * 16 + c) * HS_ + cs * 32 + g * 8);

  f32x4 acc[2][8];
#pragma unroll
  for (int i = 0; i < 2; ++i)
#pragma unroll
    for (int j = 0; j < 8; ++j) acc[i][j] = 0.f;
  float mrun[2] = {-INFINITY, -INFINITY};
  float lrun[2] = {0.f, 0.f};

  const int nk = qt + 1;
  for (int kt = 0; kt < nk; ++kt) {
    const int kbase = kt * 32;
    const __bf16* kr0 = Kp + (kbase + kp) * HS_;

    f32x4 s[2][2];
#pragma unroll
    for (int i = 0; i < 2; ++i) { s[i][0] = 0.f; s[i][1] = 0.f; }
#pragma unroll
    for (int cs = 0; cs < 4; ++cs) {
      bf16x8 k0 = *reinterpret_cast<const bf16x8*>(kr0 + cs * 32 + g * 8);
      bf16x8 k1 = *reinterpret_cast<const bf16x8*>(kr0 + 4 * HS_ + cs * 32 + g * 8);
      s[0][0] = MFMA(k0, qf[0][cs], s[0][0]);
      s[0][1] = MFMA(k1, qf[0][cs], s[0][1]);
      s[1][0] = MFMA(k0, qf[1][cs], s[1][0]);
      s[1][1] = MFMA(k1, qf[1][cs], s[1][1]);
    }

    const bool maskt = (kbase + 31 > qb);   // only the diagonal tile
    bf16x8 pb[2];
#pragma unroll
    for (int rt = 0; rt < 2; ++rt) {
      float p[8];
      const int qrow = qb + rt * 16 + c;
#pragma unroll
      for (int mm = 0; mm < 2; ++mm)
#pragma unroll
        for (int r = 0; r < 4; ++r) {
          float sv = s[rt][mm][r];
          if (maskt && (kbase + 8 * g + 4 * mm + r > qrow)) sv = -INFINITY;
          p[mm * 4 + r] = sv;
        }
      float tmax = p[0];
#pragma unroll
      for (int j = 1; j < 8; ++j) tmax = fmaxf(tmax, p[j]);
      tmax = fmaxf(tmax, __shfl_xor(tmax, 16));
      tmax = fmaxf(tmax, __shfl_xor(tmax, 32));

      const float mold = mrun[rt];
      if (!__all(tmax <= mold + 8.0f)) {     // defer-max (T13)
        const float mnew  = fmaxf(mold, tmax);
        const float alpha = __expf(mold - mnew);
        mrun[rt] = mnew;
        lrun[rt] *= alpha;
#pragma unroll
        for (int db = 0; db < 8; ++db) acc[rt][db] *= alpha;
      }
      const float mcur = mrun[rt];
      float tsum = 0.f;
#pragma unroll
      for (int j = 0; j < 8; ++j) { p[j] = __expf(p[j] - mcur); tsum += p[j]; }
      tsum += __shfl_xor(tsum, 16);
      tsum += __shfl_xor(tsum, 32);
      lrun[rt] += tsum;
#pragma unroll
      for (int j = 0; j < 8; ++j) pb[rt][j] = (__bf16)p[j];  // b[j] <-> key 8g+j
    }

    const __bf16* vr = Vp + kbase + g * 8;
#pragma unroll
    for (int db = 0; db < 8; ++db) {
      bf16x8 vf = *reinterpret_cast<const bf16x8*>(vr + (size_t)(db * 16 + c) * T_);
      acc[0][db] = MFMA(vf, pb[0], acc[0][db]);
      acc[1][db] = MFMA(vf, pb[1], acc[1][db]);
    }
  }

  // epilogue: O^T regs -> LDS (padded) -> coalesced fp32 stores
  const float inv0 = 1.0f / lrun[0];
  const float inv1 = 1.0f / lrun[1];
#pragma unroll
  for (int rt = 0; rt < 2; ++rt)
#pragma unroll
    for (int db = 0; db < 8; ++db)
#pragma unroll
      for (int r = 0; r < 4; ++r)
        lds[(rt * 16 + c) * 129 + db * 16 + 4 * g + r] =
            acc[rt][db][r] * (rt ? inv1 : inv0);
  __syncthreads();
  float* op = out + ((size_t)b * T_ + qb) * HS_;
  for (int i = 0; i < 64; ++i) {
    int idx = i * 64 + l;
    op[idx] = lds[(idx >> 7) * 129 + (idx & 127)];
  }
}

// ---------------------------------------------------------------------------
extern "C" void kernel_launch(void* const* d_in, const int* in_sizes, int n_in,
                              void* d_out, int out_size, void* d_ws, size_t ws_size,
                              hipStream_t stream) {
  const float* x  = (const float*)d_in[0];
  const float* Wk = (const float*)d_in[1];
  const float* Wq = (const float*)d_in[2];
  const float* Wv = (const float*)d_in[3];
  float* out = (float*)d_out;

  char* ws = (char*)d_ws;
  __bf16* Wt = (__bf16*)ws;                              // 786,432 B
  __bf16* Qb = (__bf16*)(ws + 786432);                   // 4 MiB
  __bf16* Kb = (__bf16*)(ws + 786432 + 4194304);         // 4 MiB
  __bf16* Vt = (__bf16*)(ws + 786432 + 8388608);         // 4 MiB (transposed V)

  prep_w_kernel<<<1536, 256, 0, stream>>>(Wk, Wq, Wv, Wt);
  proj_kernel<<<dim3(128, 3), 256, 0, stream>>>(x, Wt, Qb, Kb, Vt);
  attn_kernel<<<512, 64, 0, stream>>>(Qb, Kb, Vt, out);
}

// Round 2
// 183.882 us; speedup vs baseline: 1.6900x; 1.6900x over previous
//
#include <hip/hip_runtime.h>
#include <hip/hip_bf16.h>
#include <math.h>

#define B_  4
#define T_  4096
#define C_  1024
#define HS_ 128

using bf16x8 = __attribute__((ext_vector_type(8))) __bf16;
using bf16x4 = __attribute__((ext_vector_type(4))) __bf16;
using f32x4  = __attribute__((ext_vector_type(4))) float;

#define MFMA(a, b, c) __builtin_amdgcn_mfma_f32_16x16x32_bf16(a, b, c, 0, 0, 0)

// ---------------------------------------------------------------------------
// Kernel 1: W fp32 [1024][128] -> Wt bf16 [3][128][1024] (transposed, K-contig)
// m=0: Wq (scaled by 1/sqrt(128)), m=1: Wk, m=2: Wv
// ---------------------------------------------------------------------------
__global__ __launch_bounds__(256) void prep_w_kernel(
    const float* __restrict__ Wk, const float* __restrict__ Wq,
    const float* __restrict__ Wv, __bf16* __restrict__ Wt) {
  int idx = blockIdx.x * 256 + threadIdx.x;     // 1536*256 = 393216 = 3*128*1024
  int m   = idx >> 17;
  int rem = idx & 131071;
  int n   = rem >> 10;
  int k   = rem & 1023;
  const float* W = (m == 0) ? Wq : ((m == 1) ? Wk : Wv);
  float v = W[k * HS_ + n];
  if (m == 0) v *= 0.08838834764831845f;        // fold attn scale into Q
  Wt[idx] = (__bf16)v;
}

__device__ inline bf16x8 cvt8(const float* p) {
  float4 u = *reinterpret_cast<const float4*>(p);
  float4 v = *reinterpret_cast<const float4*>(p + 4);
  bf16x8 r;
  r[0] = (__bf16)u.x; r[1] = (__bf16)u.y; r[2] = (__bf16)u.z; r[3] = (__bf16)u.w;
  r[4] = (__bf16)v.x; r[5] = (__bf16)v.y; r[6] = (__bf16)v.z; r[7] = (__bf16)v.w;
  return r;
}

// ---------------------------------------------------------------------------
// Kernel 2: projections, single pass over x (x HBM-read once, not 3x).
// Block = 32 rows of x, 4 waves. 24 (matrix, col-tile) units; wave w owns
// units [6w, 6w+6). A-frag: fp32->bf16 in-register. Q,K row-major bf16;
// V transposed [B][128][T] for the PV step's A-operand.
// ---------------------------------------------------------------------------
__global__ __launch_bounds__(256) void proj_kernel(
    const float* __restrict__ x, const __bf16* __restrict__ Wt,
    __bf16* __restrict__ Qb, __bf16* __restrict__ Kb, __bf16* __restrict__ Vt) {
  const int tid = threadIdx.x;
  const int wid = tid >> 6;
  const int l   = tid & 63;
  const int c   = l & 15;      // A-row / B-col slot
  const int g   = l >> 4;      // k-group
  const int rbase = blockIdx.x * 32;

  f32x4 acc[6][2];
#pragma unroll
  for (int i = 0; i < 6; ++i) { acc[i][0] = 0.f; acc[i][1] = 0.f; }

  const float* xr0 = x + (size_t)(rbase + c) * C_;
  const float* xr1 = xr0 + 16 * C_;

  const __bf16* wb[6];
  int mm[6], nn[6];
#pragma unroll
  for (int i = 0; i < 6; ++i) {
    int u = wid * 6 + i;
    mm[i] = u >> 3; nn[i] = u & 7;
    wb[i] = Wt + ((size_t)mm[i] * 128 + nn[i] * 16 + c) * C_;
  }

  for (int cb = 0; cb < C_; cb += 32) {
    const int co = cb + g * 8;
    bf16x8 a0 = cvt8(xr0 + co);
    bf16x8 a1 = cvt8(xr1 + co);
#pragma unroll
    for (int i = 0; i < 6; ++i) {
      bf16x8 bf = *reinterpret_cast<const bf16x8*>(wb[i] + co);
      acc[i][0] = MFMA(a0, bf, acc[i][0]);
      acc[i][1] = MFMA(a1, bf, acc[i][1]);
    }
  }

#pragma unroll
  for (int i = 0; i < 6; ++i) {
    const int m = mm[i], nt = nn[i];
    if (m < 2) {
      __bf16* dst = (m == 0) ? Qb : Kb;
#pragma unroll
      for (int rt = 0; rt < 2; ++rt)
#pragma unroll
        for (int r = 0; r < 4; ++r) {
          int row = rbase + rt * 16 + 4 * g + r;   // D row = 4g+r
          dst[(size_t)row * HS_ + nt * 16 + c] = (__bf16)acc[i][rt][r];
        }
    } else {
#pragma unroll
      for (int rt = 0; rt < 2; ++rt) {
        int row = rbase + rt * 16 + 4 * g;          // 4 consecutive rows
        int bb  = row >> 12;
        int t   = row & 4095;
        bf16x4 v4;
#pragma unroll
        for (int r = 0; r < 4; ++r) v4[r] = (__bf16)acc[i][rt][r];
        *reinterpret_cast<bf16x4*>(Vt + ((size_t)bb * HS_ + nt * 16 + c) * T_ + t) = v4;
      }
    }
  }
}

// ---------------------------------------------------------------------------
// Kernel 3: causal flash attention, 8 waves/block, intra-block split-K.
// Block = one (b, q-tile of 32 rows). Wave w processes key tiles
// kt = w, w+8, ... with private flash state; epilogue combines via
// LDS stats + 2-buffer f32 tree.
// S^T = mfma(A=K_perm, B=Q^T) so softmax stats are lane-column-local;
// P packed per-lane IS the B-frag of P^T for PV (zero cross-lane traffic).
// Complementary q-tile pairing: blocks i and i+256 have qt_i + qt_{i+256}=127
// so each CU's two resident blocks carry ~constant total work.
// ---------------------------------------------------------------------------
__global__ __launch_bounds__(512, 4) void attn_kernel(
    const __bf16* __restrict__ Qb, const __bf16* __restrict__ Kb,
    const __bf16* __restrict__ Vt, float* __restrict__ out) {
  __shared__ float sm[8][32];
  __shared__ float sl[8][32];
  __shared__ float bufA[32][132];
  __shared__ float bufB[32][132];

  const int tid = threadIdx.x;
  const int wid = tid >> 6;
  const int l   = tid & 63;
  const int c   = l & 15;
  const int g   = l >> 4;
  const int bid = blockIdx.x;
  const int h   = bid >> 2;                 // 0..127
  const int qt  = (h < 64) ? (127 - h) : (h - 64);
  const int b   = bid & 3;
  const int qb  = qt * 32;
  const int kp  = ((l & 12) << 1) | (l & 3);  // A-slot m -> key 8*(m>>2)+(m&3)

  const __bf16* Qp = Qb + (size_t)b * T_ * HS_;
  const __bf16* Kp = Kb + (size_t)b * T_ * HS_;
  const __bf16* Vp = Vt + (size_t)b * HS_ * T_;

  bf16x8 qf[2][4];
#pragma unroll
  for (int rt = 0; rt < 2; ++rt)
#pragma unroll
    for (int cs = 0; cs < 4; ++cs)
      qf[rt][cs] = *reinterpret_cast<const bf16x8*>(
          Qp + (qb + rt * 16 + c) * HS_ + cs * 32 + g * 8);

  f32x4 acc[2][8];
#pragma unroll
  for (int i = 0; i < 2; ++i)
#pragma unroll
    for (int j = 0; j < 8; ++j) acc[i][j] = 0.f;
  float mrun[2] = {-INFINITY, -INFINITY};
  float lrun[2] = {0.f, 0.f};

  for (int kt = wid; kt <= qt; kt += 8) {
    const int kbase = kt * 32;
    const __bf16* kr0 = Kp + (kbase + kp) * HS_;

    f32x4 s[2][2];
#pragma unroll
    for (int i = 0; i < 2; ++i) { s[i][0] = 0.f; s[i][1] = 0.f; }
#pragma unroll
    for (int cs = 0; cs < 4; ++cs) {
      bf16x8 k0 = *reinterpret_cast<const bf16x8*>(kr0 + cs * 32 + g * 8);
      bf16x8 k1 = *reinterpret_cast<const bf16x8*>(kr0 + 4 * HS_ + cs * 32 + g * 8);
      s[0][0] = MFMA(k0, qf[0][cs], s[0][0]);
      s[0][1] = MFMA(k1, qf[0][cs], s[0][1]);
      s[1][0] = MFMA(k0, qf[1][cs], s[1][0]);
      s[1][1] = MFMA(k1, qf[1][cs], s[1][1]);
    }

    const bool maskt = (kbase + 31 > qb);   // only the diagonal tile
    bf16x8 pb[2];
#pragma unroll
    for (int rt = 0; rt < 2; ++rt) {
      float p[8];
      const int qrow = qb + rt * 16 + c;
#pragma unroll
      for (int mm2 = 0; mm2 < 2; ++mm2)
#pragma unroll
        for (int r = 0; r < 4; ++r) {
          float sv = s[rt][mm2][r];
          if (maskt && (kbase + 8 * g + 4 * mm2 + r > qrow)) sv = -INFINITY;
          p[mm2 * 4 + r] = sv;
        }
      float tmax = p[0];
#pragma unroll
      for (int j = 1; j < 8; ++j) tmax = fmaxf(tmax, p[j]);
      tmax = fmaxf(tmax, __shfl_xor(tmax, 16));
      tmax = fmaxf(tmax, __shfl_xor(tmax, 32));

      const float mold = mrun[rt];
      if (!__all(tmax <= mold + 8.0f)) {     // defer-max (T13)
        const float mnew  = fmaxf(mold, tmax);
        const float alpha = __expf(mold - mnew);
        mrun[rt] = mnew;
        lrun[rt] *= alpha;
#pragma unroll
        for (int db = 0; db < 8; ++db) acc[rt][db] *= alpha;
      }
      const float mcur = mrun[rt];
      float tsum = 0.f;
#pragma unroll
      for (int j = 0; j < 8; ++j) { p[j] = __expf(p[j] - mcur); tsum += p[j]; }
      tsum += __shfl_xor(tsum, 16);
      tsum += __shfl_xor(tsum, 32);
      lrun[rt] += tsum;
#pragma unroll
      for (int j = 0; j < 8; ++j) pb[rt][j] = (__bf16)p[j];  // b[j] <-> key 8g+j
    }

    const __bf16* vr = Vp + kbase + g * 8;
#pragma unroll
    for (int db = 0; db < 8; ++db) {
      bf16x8 vf = *reinterpret_cast<const bf16x8*>(vr + (size_t)(db * 16 + c) * T_);
      acc[0][db] = MFMA(vf, pb[0], acc[0][db]);
      acc[1][db] = MFMA(vf, pb[1], acc[1][db]);
    }
  }

  // ---- combine the 8 waves' partial (m, l, O) ----
  if (g == 0) {
    sm[wid][c]      = mrun[0];
    sm[wid][16 + c] = mrun[1];
    sl[wid][c]      = lrun[0];
    sl[wid][16 + c] = lrun[1];
  }
  __syncthreads();

  float linv[2];
#pragma unroll
  for (int rt = 0; rt < 2; ++rt) {
    const int q = rt * 16 + c;
    float ms = sm[0][q];
#pragma unroll
    for (int w = 1; w < 8; ++w) ms = fmaxf(ms, sm[w][q]);
    float ls = 0.f;
#pragma unroll
    for (int w = 0; w < 8; ++w) ls += __expf(sm[w][q] - ms) * sl[w][q];
    const float alpha = __expf(mrun[rt] - ms);   // 0 if this wave had no tiles
#pragma unroll
    for (int db = 0; db < 8; ++db) acc[rt][db] *= alpha;
    linv[rt] = 1.0f / ls;
  }

  auto store_buf = [&](float(*buf)[132]) {
#pragma unroll
    for (int rt = 0; rt < 2; ++rt)
#pragma unroll
      for (int db = 0; db < 8; ++db)
        *reinterpret_cast<f32x4*>(&buf[rt * 16 + c][db * 16 + 4 * g]) = acc[rt][db];
  };
  auto add_buf = [&](float(*buf)[132]) {
#pragma unroll
    for (int rt = 0; rt < 2; ++rt)
#pragma unroll
      for (int db = 0; db < 8; ++db)
        acc[rt][db] += *reinterpret_cast<f32x4*>(&buf[rt * 16 + c][db * 16 + 4 * g]);
  };

  if (wid == 4) store_buf(bufA);
  if (wid == 5) store_buf(bufB);
  __syncthreads();
  if (wid == 0) add_buf(bufA);          // 0+4
  if (wid == 1) add_buf(bufB);          // 1+5
  __syncthreads();
  if (wid == 6) store_buf(bufA);
  if (wid == 7) store_buf(bufB);
  __syncthreads();
  if (wid == 2) add_buf(bufA);          // 2+6
  if (wid == 3) add_buf(bufB);          // 3+7
  __syncthreads();
  if (wid == 2) store_buf(bufA);
  if (wid == 3) store_buf(bufB);
  __syncthreads();
  if (wid == 0) add_buf(bufA);          // 0+4+2+6
  if (wid == 1) add_buf(bufB);          // 1+5+3+7
  __syncthreads();
  if (wid == 1) store_buf(bufA);
  __syncthreads();

  if (wid == 0) {
    add_buf(bufA);                      // full sum
    float* op = out + ((size_t)b * T_ + qb) * HS_;
#pragma unroll
    for (int rt = 0; rt < 2; ++rt)
#pragma unroll
      for (int db = 0; db < 8; ++db) {
        f32x4 v = acc[rt][db] * linv[rt];
        *reinterpret_cast<f32x4*>(op + (rt * 16 + c) * HS_ + db * 16 + 4 * g) = v;
      }
  }
}

// ---------------------------------------------------------------------------
extern "C" void kernel_launch(void* const* d_in, const int* in_sizes, int n_in,
                              void* d_out, int out_size, void* d_ws, size_t ws_size,
                              hipStream_t stream) {
  const float* x  = (const float*)d_in[0];
  const float* Wk = (const float*)d_in[1];
  const float* Wq = (const float*)d_in[2];
  const float* Wv = (const float*)d_in[3];
  float* out = (float*)d_out;

  char* ws = (char*)d_ws;
  __bf16* Wt = (__bf16*)ws;                              // 786,432 B
  __bf16* Qb = (__bf16*)(ws + 786432);                   // 4 MiB
  __bf16* Kb = (__bf16*)(ws + 786432 + 4194304);         // 4 MiB
  __bf16* Vt = (__bf16*)(ws + 786432 + 8388608);         // 4 MiB (transposed V)

  prep_w_kernel<<<1536, 256, 0, stream>>>(Wk, Wq, Wv, Wt);
  proj_kernel<<<512, 256, 0, stream>>>(x, Wt, Qb, Kb, Vt);
  attn_kernel<<<512, 512, 0, stream>>>(Qb, Kb, Vt, out);
}